// Round 10
// baseline (262.324 us; speedup 1.0000x reference)
//
#include <hip/hip_runtime.h>

typedef unsigned short u16;
typedef unsigned int u32;

typedef __bf16 bfrag __attribute__((ext_vector_type(8)));   // 8 bf16 = 4 VGPRs (MFMA A/B operand)
typedef float f32x4 __attribute__((ext_vector_type(4)));    // MFMA C/D operand (16x16)
typedef float f32x16 __attribute__((ext_vector_type(16)));  // MFMA C/D operand (32x32)
typedef float f32x2 __attribute__((ext_vector_type(2)));

// ---------- bf16 helpers ----------
__device__ __forceinline__ float b2f(u16 h) {
    u32 u = ((u32)h) << 16;
    return __builtin_bit_cast(float, u);
}
__device__ __forceinline__ u16 f2b(float f) {   // RNE
    u32 u = __builtin_bit_cast(u32, f);
    u += 0x7fffu + ((u >> 16) & 1u);
    return (u16)(u >> 16);
}
// packed RNE f32->bf16 pair: dst.lo = bf16(lo), dst.hi = bf16(hi).
__device__ __forceinline__ u32 cvtpk(float lo, float hi) {
    u32 r;
    asm("v_cvt_pk_bf16_f32 %0, %1, %2" : "=v"(r) : "v"(lo), "v"(hi));
    return r;
}

// ---------- fast exp2 ----------
#if defined(__has_builtin)
#if __has_builtin(__builtin_amdgcn_exp2f)
#define EXP2(x) __builtin_amdgcn_exp2f(x)
#endif
#endif
#ifndef EXP2
#define EXP2(x) exp2f(x)
#endif

// ---------- async global->LDS (width 16), with fallback ----------
#if defined(__has_builtin)
#if __has_builtin(__builtin_amdgcn_global_load_lds)
#define HAS_GLL 1
#endif
#endif
#ifndef HAS_GLL
#define HAS_GLL 0
#endif

#if HAS_GLL
typedef __attribute__((address_space(1))) const u32 as1_u32;
typedef __attribute__((address_space(3))) u32 as3_u32;
__device__ __forceinline__ void gl_lds16(const u16* g, u16* l) {
    // dest: wave-uniform base; HW stores lane's 16B at base + lane*16
    __builtin_amdgcn_global_load_lds((as1_u32*)g, (as3_u32*)l, 16, 0, 0);
}
#endif

// ---------- permlane32_swap (cross-half exchange), with bpermute fallback ----
#if defined(__has_builtin)
#if __has_builtin(__builtin_amdgcn_permlane32_swap)
#define HAS_PLS 1
#endif
#endif
#ifndef HAS_PLS
#define HAS_PLS 0
#endif

// out0[lane<32]=a(self), out0[lane>=32]=b[lane-32];
// out1[lane<32]=a[lane+32], out1[lane>=32]=b(self)
__device__ __forceinline__ void plswap(u32 a, u32 b, u32& o0, u32& o1) {
#if HAS_PLS
    auto r = __builtin_amdgcn_permlane32_swap((int)a, (int)b, false, false);
    o0 = (u32)r[0];
    o1 = (u32)r[1];
#else
    int idx = ((int)(threadIdx.x & 63) ^ 32) << 2;
    u32 ca = (u32)__builtin_amdgcn_ds_bpermute(idx, (int)a);
    u32 cb = (u32)__builtin_amdgcn_ds_bpermute(idx, (int)b);
    bool hi = (threadIdx.x & 63) >= 32;
    o0 = hi ? cb : a;
    o1 = hi ? b : ca;
#endif
}

// ---------- bijective chunked XCD swizzle (T1, m157/m204) ----------
__device__ __forceinline__ void xcd_swizzle(int& bxn, int& bym) {
    int gx = gridDim.x;
    int nwg = gx * gridDim.y;
    int orig = blockIdx.x + gx * blockIdx.y;
    int nid = orig;
    if ((nwg & 7) == 0) {
        int cpx = nwg >> 3;
        nid = (orig & 7) * cpx + (orig >> 3);
    }
    bxn = nid % gx;
    bym = nid / gx;
}

// Problem constants
#define BATCH 4
#define SEQ   2048
#define DM    1024
#define NH    16
#define HD    64
#define MB    32
#define STOK  (BATCH * SEQ)   // 8192

// log2(e)/sqrt(32): folded into q_enc so P = exp2(S) directly
#define QSCALE 0.25503524337503433f
#define TWOLOG2E 2.8853900817779268f   // 2*log2(e), for tanh via exp2

__device__ __forceinline__ void storeC(u16* C, size_t idx, float v)   { C[idx] = f2b(v); }
__device__ __forceinline__ void storeC(float* C, size_t idx, float v) { C[idx] = v; }

// =====================================================================
// fp32 -> bf16 conversion prepass: 3 jobs in one launch (x, Wv, Wo)
// =====================================================================
__global__ __launch_bounds__(256) void cvt3_f32_bf16(
    const float* __restrict__ a, const float* __restrict__ b,
    const float* __restrict__ c,
    u16* __restrict__ da, u16* __restrict__ db, u16* __restrict__ dc,
    int n8a, int n8bc)
{
    const int job = blockIdx.y;
    const float* s = (job == 0) ? a : ((job == 1) ? b : c);
    u16* d = (job == 0) ? da : ((job == 1) ? db : dc);
    int n8 = (job == 0) ? n8a : n8bc;
    int i = blockIdx.x * 256 + threadIdx.x;
    if (i >= n8) return;
    const float4* sp = (const float4*)s + (size_t)i * 2;
    float4 x = sp[0], y = sp[1];
    u16 t[8] = { f2b(x.x), f2b(x.y), f2b(x.z), f2b(x.w),
                 f2b(y.x), f2b(y.y), f2b(y.z), f2b(y.w) };
    ((uint4*)d)[i] = *(uint4*)t;
}

// =====================================================================
// Folded encoders: CqkT[r][d], r = qk*512 + h*32 + m, d = 0..1023
//   CqkT[r][d] = sum_dh W[h*64+dh][d] * Wenc[h][dh][m]   (W = Wq or Wk)
// =====================================================================
__global__ __launch_bounds__(256) void build_cqk(
    const float* __restrict__ Wq, const float* __restrict__ Wk,
    const float* __restrict__ Wenc, u16* __restrict__ CqkT)
{
    const int dblk = blockIdx.x;           // d-block of 128
    const int qk   = blockIdx.y >> 4;      // 0=q, 1=k
    const int h    = blockIdx.y & 15;
    const float* W = qk ? Wk : Wq;
    __shared__ float we[64][32];
    const int tid = threadIdx.x;

    for (int p = 0; p < 8; ++p) {
        int idx = p * 256 + tid;           // dh*32 + m
        we[idx >> 5][idx & 31] = Wenc[(size_t)h * (HD * MB) + idx];
    }
    __syncthreads();

    const int mh = tid >> 7;               // m-half 0/1
    const int d  = dblk * 128 + (tid & 127);
    float acc[16] = {};
    for (int dh = 0; dh < 64; ++dh) {
        float w = W[(size_t)(h * 64 + dh) * DM + d];
        for (int m = 0; m < 16; ++m)
            acc[m] += w * we[dh][mh * 16 + m];
    }
    u16* dst = CqkT + (size_t)(qk * 512 + h * 32 + mh * 16) * DM + d;
    for (int m = 0; m < 16; ++m)
        dst[(size_t)m * DM] = f2b(acc[m]);
}

// =====================================================================
// GEMM: C[M,N] = A[M,K] @ Bt[N,K]^T  (bf16 in, fp32 acc), BK=32.
// + chunked XCD swizzle (T1).
// =====================================================================
template <int TBM, typename TC>
__global__ __launch_bounds__(256) void gemm_bt(
    const u16* __restrict__ A, const u16* __restrict__ Bt, TC* __restrict__ C,
    int M, int Nc, int K)
{
    constexpr int FI = TBM / 32;   // row-frags per wave
    __shared__ alignas(16) u16 As[TBM * 32];
    __shared__ alignas(16) u16 Bs[128 * 32];

    const int tid  = threadIdx.x;
    const int wave = tid >> 6;
    const int lane = tid & 63;
    const int quad = lane >> 4;
    const int lrow = lane & 15;
    int bxn, bym;
    xcd_swizzle(bxn, bym);
    const int bm = bym * TBM;
    const int bn = bxn * 128;
    const int wm = (wave & 1) * (TBM / 2);
    const int wn = (wave >> 1) * 64;

    f32x4 acc[FI][4] = {};

    for (int k0 = 0; k0 < K; k0 += 32) {
#if HAS_GLL
        for (int p = 0; p < TBM / 64; ++p) {
            int cbase = wave * TBM + p * 64;       // wave-uniform
            int cme   = cbase + lane;
            int row = cme >> 2, col = (cme & 3) * 8;
            gl_lds16(&A[(size_t)(bm + row) * K + k0 + col], &As[(size_t)cbase * 8]);
        }
        for (int p = 0; p < 2; ++p) {
            int cbase = wave * 128 + p * 64;
            int cme   = cbase + lane;
            int row = cme >> 2, col = (cme & 3) * 8;
            gl_lds16(&Bt[(size_t)(bn + row) * K + k0 + col], &Bs[(size_t)cbase * 8]);
        }
#else
        for (int p = 0; p < TBM / 64; ++p) {
            int idx = p * 256 + tid, row = idx >> 2, col = (idx & 3) * 8;
            *(uint4*)&As[row * 32 + col] = *(const uint4*)&A[(size_t)(bm + row) * K + k0 + col];
        }
        for (int p = 0; p < 2; ++p) {
            int idx = p * 256 + tid, row = idx >> 2, col = (idx & 3) * 8;
            *(uint4*)&Bs[row * 32 + col] = *(const uint4*)&Bt[(size_t)(bn + row) * K + k0 + col];
        }
#endif
        __syncthreads();

        bfrag af[FI], bfv[4];
        for (int i = 0; i < FI; ++i)
            af[i] = *(const bfrag*)&As[(wm + i * 16 + lrow) * 32 + quad * 8];
        for (int j = 0; j < 4; ++j)
            bfv[j] = *(const bfrag*)&Bs[(wn + j * 16 + lrow) * 32 + quad * 8];

        for (int i = 0; i < FI; ++i)
            for (int j = 0; j < 4; ++j)
                acc[i][j] = __builtin_amdgcn_mfma_f32_16x16x32_bf16(af[i], bfv[j], acc[i][j], 0, 0, 0);
        __syncthreads();
    }

    for (int i = 0; i < FI; ++i)
        for (int j = 0; j < 4; ++j)
            for (int r = 0; r < 4; ++r) {
                int row = bm + wm + i * 16 + quad * 4 + r;
                int col = bn + wn + j * 16 + lrow;
                storeC(C, (size_t)row * Nc + col, acc[i][j][r]);
            }
}

// =====================================================================
// Merged enc+V GEMM: C[8192,2048] = xb @ Bc^T, Bc = [CqkT ; Wv] (2048x1024).
// BK=32 + chunked XCD swizzle (T1).
// =====================================================================
__global__ __launch_bounds__(256) void gemm_encv(
    const u16* __restrict__ A, const u16* __restrict__ Bt,
    u16* __restrict__ qe, u16* __restrict__ ke, u16* __restrict__ Vt)
{
    __shared__ alignas(16) u16 As[128 * 32];
    __shared__ alignas(16) u16 Bs[128 * 32];

    const int tid  = threadIdx.x;
    const int wave = tid >> 6;
    const int lane = tid & 63;
    const int quad = lane >> 4;
    const int lrow = lane & 15;
    int bxn, bym;
    xcd_swizzle(bxn, bym);
    const int bm = bym * 128;
    const int bn = bxn * 128;
    const int wm = (wave & 1) * 64;
    const int wn = (wave >> 1) * 64;

    f32x4 acc[4][4] = {};

    for (int k0 = 0; k0 < DM; k0 += 32) {
#if HAS_GLL
        for (int p = 0; p < 2; ++p) {
            int cbase = wave * 128 + p * 64;
            int cme   = cbase + lane;
            int row = cme >> 2, col = (cme & 3) * 8;
            gl_lds16(&A[(size_t)(bm + row) * DM + k0 + col], &As[(size_t)cbase * 8]);
            gl_lds16(&Bt[(size_t)(bn + row) * DM + k0 + col], &Bs[(size_t)cbase * 8]);
        }
#else
        for (int p = 0; p < 2; ++p) {
            int idx = p * 256 + tid, row = idx >> 2, col = (idx & 3) * 8;
            *(uint4*)&As[row * 32 + col] = *(const uint4*)&A[(size_t)(bm + row) * DM + k0 + col];
            *(uint4*)&Bs[row * 32 + col] = *(const uint4*)&Bt[(size_t)(bn + row) * DM + k0 + col];
        }
#endif
        __syncthreads();

        bfrag af[4], bfv[4];
        for (int i = 0; i < 4; ++i)
            af[i] = *(const bfrag*)&As[(wm + i * 16 + lrow) * 32 + quad * 8];
        for (int j = 0; j < 4; ++j)
            bfv[j] = *(const bfrag*)&Bs[(wn + j * 16 + lrow) * 32 + quad * 8];

        for (int i = 0; i < 4; ++i)
            for (int j = 0; j < 4; ++j)
                acc[i][j] = __builtin_amdgcn_mfma_f32_16x16x32_bf16(af[i], bfv[j], acc[i][j], 0, 0, 0);
        __syncthreads();
    }

    if (bn < 1024) {
        // ---- encoder epilogue: tanh, scatter to qe/ke [B,H,N,32] ----
        for (int i = 0; i < 4; ++i)
            for (int j = 0; j < 4; ++j) {
                int col = bn + wn + j * 16 + lrow;     // qk*512 + h*32 + m
                int hh = (col >> 5) & 15;
                int mm = col & 31;
                u16* dst = (col < 512) ? qe : ke;      // uniform per j (16-wide frag)
                float qs = (col < 512) ? QSCALE : 1.0f;
                for (int r = 0; r < 4; ++r) {
                    int row = bm + wm + i * 16 + quad * 4 + r;     // token
                    int bb = row >> 11, nn = row & 2047;
                    float e = EXP2(acc[i][j][r] * TWOLOG2E);
                    float t = (1.f - 2.f / (e + 1.f)) * qs;
                    dst[((size_t)(bb * NH + hh) * SEQ + nn) * MB + mm] = f2b(t);
                }
            }
    } else {
        // ---- V epilogue: transposed store (4 consecutive tokens per lane) ----
        for (int i = 0; i < 4; ++i)
            for (int j = 0; j < 4; ++j) {
                int col = bn - 1024 + wn + j * 16 + lrow;  // v-dim: h*64 + d
                int hh = col >> 6, dd = col & 63;
                int row0 = bm + wm + i * 16 + quad * 4;    // token base
                int bb = row0 >> 11, nn = row0 & 2047;
                u16 t4[4] = { f2b(acc[i][j][0]), f2b(acc[i][j][1]),
                              f2b(acc[i][j][2]), f2b(acc[i][j][3]) };
                *(uint2*)&Vt[((size_t)(bb * NH + hh) * HD + dd) * SEQ + nn] = *(uint2*)t4;
            }
    }
}

// =====================================================================
// Flash attention v13: K direct-from-global (register-prefetched),
// V in LDS dbuf (unchanged from v10).
// v10 post-mortem: pipes 72% busy; remaining tax = stage+drain+lockstep
// (m233 pattern). v11 showed K's global pattern (32 rows x 64B, L2-hit)
// is latency-tolerant when register-pipelined; it was V's 4KB-stride
// loads that broke v11. So: drop Kt staging; K frags load global->reg
// one tile ahead (2-set, statically 2-unrolled). Removes per iter:
// 1 gl_lds16 from the drain, 4 of 12 ds_read_b128 (-33% LDS pipe),
// the K swizzle VALU, 8KB LDS. V path and all numerics identical.
// =====================================================================
__device__ __forceinline__ bfrag pack_half(const f32x16& St, int kc, f32x2& dacc)
{
    float e0 = EXP2(St[8 * kc + 0]);
    float e1 = EXP2(St[8 * kc + 1]);
    float e2 = EXP2(St[8 * kc + 2]);
    float e3 = EXP2(St[8 * kc + 3]);
    float e4 = EXP2(St[8 * kc + 4]);
    float e5 = EXP2(St[8 * kc + 5]);
    float e6 = EXP2(St[8 * kc + 6]);
    float e7 = EXP2(St[8 * kc + 7]);
    f32x2 p0 = {e0, e1}, p1 = {e2, e3}, p2 = {e4, e5}, p3 = {e6, e7};
    dacc += (p0 + p1) + (p2 + p3);
    u32 A0 = cvtpk(e0, e1), A1 = cvtpk(e2, e3);
    u32 B0 = cvtpk(e4, e5), B1 = cvtpk(e6, e7);
    u32 w0, w1, w2, w3;
    plswap(A0, B0, w0, w2);   // w0: keys {0,1}; w2: keys {4,5}  (+kc*16+hi*8)
    plswap(A1, B1, w1, w3);   // w1: keys {2,3}; w3: keys {6,7}
    uint4 words = { w0, w1, w2, w3 };
    return __builtin_bit_cast(bfrag, words);
}

__device__ __forceinline__ void fa_step(
    bfrag k00, bfrag k01, bfrag k10, bfrag k11,
    bfrag qf0, bfrag qf1, const u16* __restrict__ VtC,
    int vsw, int r31, int hi,
    f32x16& Oa0, f32x16& Oa1, f32x2& dacc)
{
    const f32x16 zero16 = {};
    bfrag pf[2][2];   // [kt][kc]

    __builtin_amdgcn_s_setprio(1);
    f32x16 St0 = __builtin_amdgcn_mfma_f32_32x32x16_bf16(k00, qf0, zero16, 0, 0, 0);
    St0 = __builtin_amdgcn_mfma_f32_32x32x16_bf16(k01, qf1, St0, 0, 0, 0);
    __builtin_amdgcn_s_setprio(0);
    pf[0][0] = pack_half(St0, 0, dacc);
    pf[0][1] = pack_half(St0, 1, dacc);

    __builtin_amdgcn_s_setprio(1);
    f32x16 St1 = __builtin_amdgcn_mfma_f32_32x32x16_bf16(k10, qf0, zero16, 0, 0, 0);
    St1 = __builtin_amdgcn_mfma_f32_32x32x16_bf16(k11, qf1, St1, 0, 0, 0);
    __builtin_amdgcn_s_setprio(0);
    pf[1][0] = pack_half(St1, 0, dacc);
    pf[1][1] = pack_half(St1, 1, dacc);

    __builtin_amdgcn_s_setprio(1);
    const u16* vrow0 = &VtC[(size_t)r31 * 64];
    const u16* vrow1 = &VtC[(size_t)(32 + r31) * 64];
    for (int kt = 0; kt < 2; ++kt)
        for (int kc = 0; kc < 2; ++kc) {
            int ch = ((kt * 4 + kc * 2 + hi) ^ vsw) * 8;
            bfrag vf0 = *(const bfrag*)&vrow0[ch];
            Oa0 = __builtin_amdgcn_mfma_f32_32x32x16_bf16(vf0, pf[kt][kc], Oa0, 0, 0, 0);
            bfrag vf1 = *(const bfrag*)&vrow1[ch];
            Oa1 = __builtin_amdgcn_mfma_f32_32x32x16_bf16(vf1, pf[kt][kc], Oa1, 0, 0, 0);
        }
    __builtin_amdgcn_s_setprio(0);
}

#define K_LD(p, a0, a1, a2, a3) do { \
    a0 = *(const bfrag*)(p); \
    a1 = *(const bfrag*)((p) + 16); \
    a2 = *(const bfrag*)((p) + 32 * MB); \
    a3 = *(const bfrag*)((p) + 32 * MB + 16); } while (0)

__global__ __launch_bounds__(256, 4) void flash_attn(
    const u16* __restrict__ qe,   // [B,H,N,32], pre-scaled
    const u16* __restrict__ ke,   // [B,H,N,32]
    const u16* __restrict__ Vt,   // [B*H*64, 2048]
    u16* __restrict__ AO)         // [S, 1024]
{
    const int h = blockIdx.x, b = blockIdx.y, qt = blockIdx.z;
    const int tid  = threadIdx.x;
    const int wave = tid >> 6;
    const int lane = tid & 63;
    const int r31  = lane & 31;
    const int hi   = lane >> 5;

    __shared__ alignas(16) u16 Vtile[2][64 * 64];  // 16 KB dbuf [d][key-chunk swz]

    const size_t bhh = (size_t)(b * NH + h);
    const u16* keb = ke + bhh * SEQ * MB;
    const u16* qeb = qe + bhh * SEQ * MB;
    const u16* vtb = Vt + bhh * HD * SEQ;

    const int q0w = qt * 128 + wave * 32;

    // ---- V staging source pointers (pre-swizzled global addresses) ----
    const int d0 = wave * 8 + (lane >> 3);
    const int c0 = lane & 7;
    const int g0 = (c0 ^ (d0 & 7)) * 8;                    // (d0+32)&7 == d0&7
    const u16* vsrc0 = vtb + (size_t)d0 * SEQ + g0;        // += 64/iter
    const u16* vsrc1 = vtb + (size_t)(d0 + 32) * SEQ + g0;

    // ---- prologue: V tile 0 -> buf0; K tile 0 -> registers ----
#if HAS_GLL
    gl_lds16(vsrc0, Vtile[0] + wave * 512);
    gl_lds16(vsrc1, Vtile[0] + 2048 + wave * 512);
#else
    *(uint4*)&Vtile[0][d0 * 64 + c0 * 8] = *(const uint4*)vsrc0;
    *(uint4*)&Vtile[0][(d0 + 32) * 64 + c0 * 8] = *(const uint4*)vsrc1;
#endif
    vsrc0 += 64;
    vsrc1 += 64;

    // per-lane K pointer: row = tile*64 + kt*32 + r31, col = ms*16 + hi*8
    const u16* kp = keb + (size_t)r31 * MB + hi * 8;
    bfrag kA0, kA1, kA2, kA3;   // [kt=0][ms=0,1], [kt=1][ms=0,1]
    bfrag kB0, kB1, kB2, kB3;
    K_LD(kp, kA0, kA1, kA2, kA3);
    kp += 64 * MB;

    // Q frags (hoisted): B-frag col=q0w+r31, k = ms*16 + hi*8 + j
    bfrag qf0, qf1;
    {
        const u16* qrow = qeb + (size_t)(q0w + r31) * MB;
        qf0 = *(const bfrag*)&qrow[hi * 8];
        qf1 = *(const bfrag*)&qrow[16 + hi * 8];
    }

    f32x16 Oa0 = {}, Oa1 = {};    // [dt]: D[d = dt*32 + drow(reg,hi)][q = r31]
    f32x2 dacc = {0.f, 0.f};      // per-lane partial softmax denominator
    const int vsw = r31 & 7;

    for (int c = 0; c < 32; c += 2) {
        // ---- even sub-iter: compute (kA, Vtile[0]); prefetch c+1 ----
        __syncthreads();   // drains V-lds + K reg loads for tile c
        {
#if HAS_GLL
            gl_lds16(vsrc0, Vtile[1] + wave * 512);
            gl_lds16(vsrc1, Vtile[1] + 2048 + wave * 512);
#else
            *(uint4*)&Vtile[1][d0 * 64 + c0 * 8] = *(const uint4*)vsrc0;
            *(uint4*)&Vtile[1][(d0 + 32) * 64 + c0 * 8] = *(const uint4*)vsrc1;
#endif
            vsrc0 += 64;
            vsrc1 += 64;
            K_LD(kp, kB0, kB1, kB2, kB3);
            kp += 64 * MB;
        }
        fa_step(kA0, kA1, kA2, kA3, qf0, qf1, Vtile[0], vsw, r31, hi, Oa0, Oa1, dacc);

        // ---- odd sub-iter: compute (kB, Vtile[1]); prefetch c+2 ----
        __syncthreads();
        if (c + 2 < 32) {
#if HAS_GLL
            gl_lds16(vsrc0, Vtile[0] + wave * 512);
            gl_lds16(vsrc1, Vtile[0] + 2048 + wave * 512);
#else
            *(uint4*)&Vtile[0][d0 * 64 + c0 * 8] = *(const uint4*)vsrc0;
            *(uint4*)&Vtile[0][(d0 + 32) * 64 + c0 * 8] = *(const uint4*)vsrc1;
#endif
            vsrc0 += 64;
            vsrc1 += 64;
            K_LD(kp, kA0, kA1, kA2, kA3);
            kp += 64 * MB;
        }
        fa_step(kB0, kB1, kB2, kB3, qf0, qf1, Vtile[1], vsw, r31, hi, Oa0, Oa1, dacc);
    }

    // ---- finish den: self-half + partner-half (lane r31 <-> r31+32, same q)
    float dsum = dacc[0] + dacc[1];
    u32 o0, o1;
    plswap(__builtin_bit_cast(u32, dsum), __builtin_bit_cast(u32, dsum), o0, o1);
    float den = __builtin_bit_cast(float, o0) + __builtin_bit_cast(float, o1);

    // epilogue: lane owns q = q0w + r31; cols d = dt*32 + 8*g + 4*hi + i
    {
        float inv = 1.0f / den;
        u16* aob = AO + (size_t)(b * SEQ + q0w + r31) * DM + h * HD;
        for (int g = 0; g < 4; ++g) {
            u16 t4[4] = { f2b(Oa0[g * 4 + 0] * inv), f2b(Oa0[g * 4 + 1] * inv),
                          f2b(Oa0[g * 4 + 2] * inv), f2b(Oa0[g * 4 + 3] * inv) };
            *(uint2*)&aob[g * 8 + hi * 4] = *(uint2*)t4;
        }
        for (int g = 0; g < 4; ++g) {
            u16 t4[4] = { f2b(Oa1[g * 4 + 0] * inv), f2b(Oa1[g * 4 + 1] * inv),
                          f2b(Oa1[g * 4 + 2] * inv), f2b(Oa1[g * 4 + 3] * inv) };
            *(uint2*)&aob[32 + g * 8 + hi * 4] = *(uint2*)t4;
        }
    }
}

// =====================================================================
extern "C" void kernel_launch(void* const* d_in, const int* in_sizes, int n_in,
                              void* d_out, int out_size, void* d_ws, size_t ws_size,
                              hipStream_t stream) {
    const float* x    = (const float*)d_in[0];
    const float* Wq   = (const float*)d_in[1];
    const float* Wk   = (const float*)d_in[2];
    const float* Wv   = (const float*)d_in[3];
    const float* Wenc = (const float*)d_in[4];
    const float* Wo   = (const float*)d_in[5];
    float* out = (float*)d_out;

    const size_t MB1 = (size_t)1024 * 1024;
    char* ws = (char*)d_ws;
    u16* AO   = (u16*)(ws);            // 16M [S,1024]
    u16* Wo_b = (u16*)(ws + 16 * MB1); //  2M
    u16* Bc   = (u16*)(ws + 18 * MB1); //  4M [2048][1024]: rows 0-1023 CqkT, 1024-2047 Wv
    u16* Vt   = (u16*)(ws + 24 * MB1); // 16M [B*H*64, 2048]
    u16* qe   = (u16*)(ws + 48 * MB1); //  8M [B,H,N,32]
    u16* ke   = (u16*)(ws + 56 * MB1); //  8M

    u16* xb = (u16*)d_out;             // 16M bf16 x (d_out scratch; dead before final store)
    u16* wvb = Bc + (size_t)1024 * DM; // Wv bf16 rows of Bc

    cvt3_f32_bf16<<<dim3(STOK * DM / 8 / 256, 3), 256, 0, stream>>>(
        x, Wv, Wo, xb, wvb, Wo_b, STOK * DM / 8, DM * DM / 8);
    build_cqk<<<dim3(8, 32), 256, 0, stream>>>(Wq, Wk, Wenc, Bc);

    gemm_encv<<<dim3(2048 / 128, STOK / 128), 256, 0, stream>>>(xb, Bc, qe, ke, Vt);

    flash_attn<<<dim3(NH, BATCH, SEQ / 128), 256, 0, stream>>>(qe, ke, Vt, AO);

    gemm_bt<64, float><<<dim3(DM / 128, STOK / 64), 256, 0, stream>>>(AO, Wo_b, out, STOK, DM, DM);
}

// Round 11
// 251.498 us; speedup vs baseline: 1.0430x; 1.0430x over previous
//
#include <hip/hip_runtime.h>

typedef unsigned short u16;
typedef unsigned int u32;

typedef __bf16 bfrag __attribute__((ext_vector_type(8)));   // 8 bf16 = 4 VGPRs (MFMA A/B operand)
typedef float f32x4 __attribute__((ext_vector_type(4)));    // MFMA C/D operand (16x16)
typedef float f32x16 __attribute__((ext_vector_type(16)));  // MFMA C/D operand (32x32)
typedef float f32x2 __attribute__((ext_vector_type(2)));

// ---------- bf16 helpers ----------
__device__ __forceinline__ float b2f(u16 h) {
    u32 u = ((u32)h) << 16;
    return __builtin_bit_cast(float, u);
}
__device__ __forceinline__ u16 f2b(float f) {   // RNE
    u32 u = __builtin_bit_cast(u32, f);
    u += 0x7fffu + ((u >> 16) & 1u);
    return (u16)(u >> 16);
}
// packed RNE f32->bf16 pair: dst.lo = bf16(lo), dst.hi = bf16(hi).
__device__ __forceinline__ u32 cvtpk(float lo, float hi) {
    u32 r;
    asm("v_cvt_pk_bf16_f32 %0, %1, %2" : "=v"(r) : "v"(lo), "v"(hi));
    return r;
}

// ---------- fast exp2 ----------
#if defined(__has_builtin)
#if __has_builtin(__builtin_amdgcn_exp2f)
#define EXP2(x) __builtin_amdgcn_exp2f(x)
#endif
#endif
#ifndef EXP2
#define EXP2(x) exp2f(x)
#endif

// ---------- async global->LDS (width 16), with fallback ----------
#if defined(__has_builtin)
#if __has_builtin(__builtin_amdgcn_global_load_lds)
#define HAS_GLL 1
#endif
#endif
#ifndef HAS_GLL
#define HAS_GLL 0
#endif

#if HAS_GLL
typedef __attribute__((address_space(1))) const u32 as1_u32;
typedef __attribute__((address_space(3))) u32 as3_u32;
__device__ __forceinline__ void gl_lds16(const u16* g, u16* l) {
    // dest: wave-uniform base; HW stores lane's 16B at base + lane*16
    __builtin_amdgcn_global_load_lds((as1_u32*)g, (as3_u32*)l, 16, 0, 0);
}
#endif

// ---------- permlane32_swap (cross-half exchange), with bpermute fallback ----
#if defined(__has_builtin)
#if __has_builtin(__builtin_amdgcn_permlane32_swap)
#define HAS_PLS 1
#endif
#endif
#ifndef HAS_PLS
#define HAS_PLS 0
#endif

// out0[lane<32]=a(self), out0[lane>=32]=b[lane-32];
// out1[lane<32]=a[lane+32], out1[lane>=32]=b(self)
__device__ __forceinline__ void plswap(u32 a, u32 b, u32& o0, u32& o1) {
#if HAS_PLS
    auto r = __builtin_amdgcn_permlane32_swap((int)a, (int)b, false, false);
    o0 = (u32)r[0];
    o1 = (u32)r[1];
#else
    int idx = ((int)(threadIdx.x & 63) ^ 32) << 2;
    u32 ca = (u32)__builtin_amdgcn_ds_bpermute(idx, (int)a);
    u32 cb = (u32)__builtin_amdgcn_ds_bpermute(idx, (int)b);
    bool hi = (threadIdx.x & 63) >= 32;
    o0 = hi ? cb : a;
    o1 = hi ? b : ca;
#endif
}

// ---------- bijective chunked XCD swizzle (T1, m157/m204) ----------
__device__ __forceinline__ void xcd_swizzle(int& bxn, int& bym) {
    int gx = gridDim.x;
    int nwg = gx * gridDim.y;
    int orig = blockIdx.x + gx * blockIdx.y;
    int nid = orig;
    if ((nwg & 7) == 0) {
        int cpx = nwg >> 3;
        nid = (orig & 7) * cpx + (orig >> 3);
    }
    bxn = nid % gx;
    bym = nid / gx;
}

// Problem constants
#define BATCH 4
#define SEQ   2048
#define DM    1024
#define NH    16
#define HD    64
#define MB    32
#define STOK  (BATCH * SEQ)   // 8192

// log2(e)/sqrt(32): folded into q_enc so P = exp2(S) directly
#define QSCALE 0.25503524337503433f
#define TWOLOG2E 2.8853900817779268f   // 2*log2(e), for tanh via exp2

__device__ __forceinline__ void storeC(u16* C, size_t idx, float v)   { C[idx] = f2b(v); }
__device__ __forceinline__ void storeC(float* C, size_t idx, float v) { C[idx] = v; }

// =====================================================================
// fp32 -> bf16 conversion prepass: 3 jobs in one launch (x, Wv, Wo)
// =====================================================================
__global__ __launch_bounds__(256) void cvt3_f32_bf16(
    const float* __restrict__ a, const float* __restrict__ b,
    const float* __restrict__ c,
    u16* __restrict__ da, u16* __restrict__ db, u16* __restrict__ dc,
    int n8a, int n8bc)
{
    const int job = blockIdx.y;
    const float* s = (job == 0) ? a : ((job == 1) ? b : c);
    u16* d = (job == 0) ? da : ((job == 1) ? db : dc);
    int n8 = (job == 0) ? n8a : n8bc;
    int i = blockIdx.x * 256 + threadIdx.x;
    if (i >= n8) return;
    const float4* sp = (const float4*)s + (size_t)i * 2;
    float4 x = sp[0], y = sp[1];
    u16 t[8] = { f2b(x.x), f2b(x.y), f2b(x.z), f2b(x.w),
                 f2b(y.x), f2b(y.y), f2b(y.z), f2b(y.w) };
    ((uint4*)d)[i] = *(uint4*)t;
}

// =====================================================================
// Folded encoders: CqkT[r][d], r = qk*512 + h*32 + m, d = 0..1023
//   CqkT[r][d] = sum_dh W[h*64+dh][d] * Wenc[h][dh][m]   (W = Wq or Wk)
// =====================================================================
__global__ __launch_bounds__(256) void build_cqk(
    const float* __restrict__ Wq, const float* __restrict__ Wk,
    const float* __restrict__ Wenc, u16* __restrict__ CqkT)
{
    const int dblk = blockIdx.x;           // d-block of 128
    const int qk   = blockIdx.y >> 4;      // 0=q, 1=k
    const int h    = blockIdx.y & 15;
    const float* W = qk ? Wk : Wq;
    __shared__ float we[64][32];
    const int tid = threadIdx.x;

    for (int p = 0; p < 8; ++p) {
        int idx = p * 256 + tid;           // dh*32 + m
        we[idx >> 5][idx & 31] = Wenc[(size_t)h * (HD * MB) + idx];
    }
    __syncthreads();

    const int mh = tid >> 7;               // m-half 0/1
    const int d  = dblk * 128 + (tid & 127);
    float acc[16] = {};
    for (int dh = 0; dh < 64; ++dh) {
        float w = W[(size_t)(h * 64 + dh) * DM + d];
        for (int m = 0; m < 16; ++m)
            acc[m] += w * we[dh][mh * 16 + m];
    }
    u16* dst = CqkT + (size_t)(qk * 512 + h * 32 + mh * 16) * DM + d;
    for (int m = 0; m < 16; ++m)
        dst[(size_t)m * DM] = f2b(acc[m]);
}

// =====================================================================
// GEMM: C[M,N] = A[M,K] @ Bt[N,K]^T  (bf16 in, fp32 acc), BK=32.
// + chunked XCD swizzle (T1).
// =====================================================================
template <int TBM, typename TC>
__global__ __launch_bounds__(256) void gemm_bt(
    const u16* __restrict__ A, const u16* __restrict__ Bt, TC* __restrict__ C,
    int M, int Nc, int K)
{
    constexpr int FI = TBM / 32;   // row-frags per wave
    __shared__ alignas(16) u16 As[TBM * 32];
    __shared__ alignas(16) u16 Bs[128 * 32];

    const int tid  = threadIdx.x;
    const int wave = tid >> 6;
    const int lane = tid & 63;
    const int quad = lane >> 4;
    const int lrow = lane & 15;
    int bxn, bym;
    xcd_swizzle(bxn, bym);
    const int bm = bym * TBM;
    const int bn = bxn * 128;
    const int wm = (wave & 1) * (TBM / 2);
    const int wn = (wave >> 1) * 64;

    f32x4 acc[FI][4] = {};

    for (int k0 = 0; k0 < K; k0 += 32) {
#if HAS_GLL
        for (int p = 0; p < TBM / 64; ++p) {
            int cbase = wave * TBM + p * 64;       // wave-uniform
            int cme   = cbase + lane;
            int row = cme >> 2, col = (cme & 3) * 8;
            gl_lds16(&A[(size_t)(bm + row) * K + k0 + col], &As[(size_t)cbase * 8]);
        }
        for (int p = 0; p < 2; ++p) {
            int cbase = wave * 128 + p * 64;
            int cme   = cbase + lane;
            int row = cme >> 2, col = (cme & 3) * 8;
            gl_lds16(&Bt[(size_t)(bn + row) * K + k0 + col], &Bs[(size_t)cbase * 8]);
        }
#else
        for (int p = 0; p < TBM / 64; ++p) {
            int idx = p * 256 + tid, row = idx >> 2, col = (idx & 3) * 8;
            *(uint4*)&As[row * 32 + col] = *(const uint4*)&A[(size_t)(bm + row) * K + k0 + col];
        }
        for (int p = 0; p < 2; ++p) {
            int idx = p * 256 + tid, row = idx >> 2, col = (idx & 3) * 8;
            *(uint4*)&Bs[row * 32 + col] = *(const uint4*)&Bt[(size_t)(bn + row) * K + k0 + col];
        }
#endif
        __syncthreads();

        bfrag af[FI], bfv[4];
        for (int i = 0; i < FI; ++i)
            af[i] = *(const bfrag*)&As[(wm + i * 16 + lrow) * 32 + quad * 8];
        for (int j = 0; j < 4; ++j)
            bfv[j] = *(const bfrag*)&Bs[(wn + j * 16 + lrow) * 32 + quad * 8];

        for (int i = 0; i < FI; ++i)
            for (int j = 0; j < 4; ++j)
                acc[i][j] = __builtin_amdgcn_mfma_f32_16x16x32_bf16(af[i], bfv[j], acc[i][j], 0, 0, 0);
        __syncthreads();
    }

    for (int i = 0; i < FI; ++i)
        for (int j = 0; j < 4; ++j)
            for (int r = 0; r < 4; ++r) {
                int row = bm + wm + i * 16 + quad * 4 + r;
                int col = bn + wn + j * 16 + lrow;
                storeC(C, (size_t)row * Nc + col, acc[i][j][r]);
            }
}

// =====================================================================
// Merged enc+V GEMM: C[8192,2048] = xb @ Bc^T, Bc = [CqkT ; Wv] (2048x1024).
// BK=32 + chunked XCD swizzle (T1).
// =====================================================================
__global__ __launch_bounds__(256) void gemm_encv(
    const u16* __restrict__ A, const u16* __restrict__ Bt,
    u16* __restrict__ qe, u16* __restrict__ ke, u16* __restrict__ Vt)
{
    __shared__ alignas(16) u16 As[128 * 32];
    __shared__ alignas(16) u16 Bs[128 * 32];

    const int tid  = threadIdx.x;
    const int wave = tid >> 6;
    const int lane = tid & 63;
    const int quad = lane >> 4;
    const int lrow = lane & 15;
    int bxn, bym;
    xcd_swizzle(bxn, bym);
    const int bm = bym * 128;
    const int bn = bxn * 128;
    const int wm = (wave & 1) * 64;
    const int wn = (wave >> 1) * 64;

    f32x4 acc[4][4] = {};

    for (int k0 = 0; k0 < DM; k0 += 32) {
#if HAS_GLL
        for (int p = 0; p < 2; ++p) {
            int cbase = wave * 128 + p * 64;
            int cme   = cbase + lane;
            int row = cme >> 2, col = (cme & 3) * 8;
            gl_lds16(&A[(size_t)(bm + row) * DM + k0 + col], &As[(size_t)cbase * 8]);
            gl_lds16(&Bt[(size_t)(bn + row) * DM + k0 + col], &Bs[(size_t)cbase * 8]);
        }
#else
        for (int p = 0; p < 2; ++p) {
            int idx = p * 256 + tid, row = idx >> 2, col = (idx & 3) * 8;
            *(uint4*)&As[row * 32 + col] = *(const uint4*)&A[(size_t)(bm + row) * DM + k0 + col];
            *(uint4*)&Bs[row * 32 + col] = *(const uint4*)&Bt[(size_t)(bn + row) * DM + k0 + col];
        }
#endif
        __syncthreads();

        bfrag af[4], bfv[4];
        for (int i = 0; i < 4; ++i)
            af[i] = *(const bfrag*)&As[(wm + i * 16 + lrow) * 32 + quad * 8];
        for (int j = 0; j < 4; ++j)
            bfv[j] = *(const bfrag*)&Bs[(wn + j * 16 + lrow) * 32 + quad * 8];

        for (int i = 0; i < 4; ++i)
            for (int j = 0; j < 4; ++j)
                acc[i][j] = __builtin_amdgcn_mfma_f32_16x16x32_bf16(af[i], bfv[j], acc[i][j], 0, 0, 0);
        __syncthreads();
    }

    if (bn < 1024) {
        // ---- encoder epilogue: tanh, scatter to qe/ke [B,H,N,32] ----
        for (int i = 0; i < 4; ++i)
            for (int j = 0; j < 4; ++j) {
                int col = bn + wn + j * 16 + lrow;     // qk*512 + h*32 + m
                int hh = (col >> 5) & 15;
                int mm = col & 31;
                u16* dst = (col < 512) ? qe : ke;      // uniform per j (16-wide frag)
                float qs = (col < 512) ? QSCALE : 1.0f;
                for (int r = 0; r < 4; ++r) {
                    int row = bm + wm + i * 16 + quad * 4 + r;     // token
                    int bb = row >> 11, nn = row & 2047;
                    float e = EXP2(acc[i][j][r] * TWOLOG2E);
                    float t = (1.f - 2.f / (e + 1.f)) * qs;
                    dst[((size_t)(bb * NH + hh) * SEQ + nn) * MB + mm] = f2b(t);
                }
            }
    } else {
        // ---- V epilogue: transposed store (4 consecutive tokens per lane) ----
        for (int i = 0; i < 4; ++i)
            for (int j = 0; j < 4; ++j) {
                int col = bn - 1024 + wn + j * 16 + lrow;  // v-dim: h*64 + d
                int hh = col >> 6, dd = col & 63;
                int row0 = bm + wm + i * 16 + quad * 4;    // token base
                int bb = row0 >> 11, nn = row0 & 2047;
                u16 t4[4] = { f2b(acc[i][j][0]), f2b(acc[i][j][1]),
                              f2b(acc[i][j][2]), f2b(acc[i][j][3]) };
                *(uint2*)&Vt[((size_t)(bb * NH + hh) * HD + dd) * SEQ + nn] = *(uint2*)t4;
            }
    }
}

// =====================================================================
// Flash attention v10 (REVERT of v13): Kt LDS staging restored.
// v13 post-mortem: K-direct-to-register dbuf across __syncthreads forced
// scratch spills (WRITE_SIZE 16.4->27MB, FETCH +2.7MB) -- the register
// pressure cost exceeded the LDS-pipe savings (bank-conflict 10.5M->4.2M
// but MfmaUtil 28->25, +9us). v10 is the measured optimum structure:
// Kt+Vtile LDS dbuf, 1 barrier/iter, in-register P transpose (T12),
// f32 den presum, cvtpk pack.
// =====================================================================
__global__ __launch_bounds__(256, 4) void flash_attn(
    const u16* __restrict__ qe,   // [B,H,N,32], pre-scaled
    const u16* __restrict__ ke,   // [B,H,N,32]
    const u16* __restrict__ Vt,   // [B*H*64, 2048]
    u16* __restrict__ AO)         // [S, 1024]
{
    const int h = blockIdx.x, b = blockIdx.y, qt = blockIdx.z;
    const int tid  = threadIdx.x;
    const int wave = tid >> 6;
    const int lane = tid & 63;
    const int r31  = lane & 31;
    const int hi   = lane >> 5;

    __shared__ alignas(16) u16 Kt[2][64 * 32];     //  8 KB dbuf [key][m-chunk swz]
    __shared__ alignas(16) u16 Vtile[2][64 * 64];  // 16 KB dbuf [d][key-chunk swz]

    const size_t bhh = (size_t)(b * NH + h);
    const u16* keb = ke + bhh * SEQ * MB;
    const u16* qeb = qe + bhh * SEQ * MB;
    const u16* vtb = Vt + bhh * HD * SEQ;

    const int q0w = qt * 128 + wave * 32;

    // ---- staging source pointers (pre-swizzled global addresses) ----
    const int klr = tid >> 2;                              // key row 0..63
    const int ksl = tid & 3;                               // 16B chunk slot
    const u16* ksrc = keb + (size_t)klr * MB + ((ksl ^ (klr & 3)) * 8);   // += 2048/iter
    const int d0 = wave * 8 + (lane >> 3);
    const int c0 = lane & 7;
    const int g0 = (c0 ^ (d0 & 7)) * 8;                    // (d0+32)&7 == d0&7
    const u16* vsrc0 = vtb + (size_t)d0 * SEQ + g0;        // += 64/iter
    const u16* vsrc1 = vtb + (size_t)(d0 + 32) * SEQ + g0;

    // ---- prologue: prefetch tile 0 into buffer 0 (drained by first barrier)
#if HAS_GLL
    gl_lds16(ksrc,  Kt[0] + wave * 512);
    gl_lds16(vsrc0, Vtile[0] + wave * 512);
    gl_lds16(vsrc1, Vtile[0] + 2048 + wave * 512);
#else
    *(uint4*)&Kt[0][klr * 32 + ksl * 8] = *(const uint4*)ksrc;
    *(uint4*)&Vtile[0][d0 * 64 + c0 * 8] = *(const uint4*)vsrc0;
    *(uint4*)&Vtile[0][(d0 + 32) * 64 + c0 * 8] = *(const uint4*)vsrc1;
#endif
    ksrc += 64 * MB;
    vsrc0 += 64;
    vsrc1 += 64;

    // Q frags (hoisted): B-frag col=q0w+r31, k = ms*16 + hi*8 + j
    bfrag qf[2];
    {
        const u16* qrow = qeb + (size_t)(q0w + r31) * MB;
        qf[0] = *(const bfrag*)&qrow[hi * 8];
        qf[1] = *(const bfrag*)&qrow[16 + hi * 8];
    }

    const f32x16 zero16 = {};

    f32x16 Oa[2] = {};     // [dt]: D[d = dt*32 + drow(reg,hi)][q = r31]
    f32x2 dacc = {0.f, 0.f};   // per-lane partial softmax denominator
    const int ksw = r31 & 3;
    const int vsw = r31 & 7;

    for (int c = 0; c < 32; ++c) {
        const int cur = c & 1, nxt = cur ^ 1;
        __syncthreads();

        if (c + 1 < 32) {
#if HAS_GLL
            gl_lds16(ksrc,  Kt[nxt] + wave * 512);
            gl_lds16(vsrc0, Vtile[nxt] + wave * 512);
            gl_lds16(vsrc1, Vtile[nxt] + 2048 + wave * 512);
#else
            *(uint4*)&Kt[nxt][klr * 32 + ksl * 8] = *(const uint4*)ksrc;
            *(uint4*)&Vtile[nxt][d0 * 64 + c0 * 8] = *(const uint4*)vsrc0;
            *(uint4*)&Vtile[nxt][(d0 + 32) * 64 + c0 * 8] = *(const uint4*)vsrc1;
#endif
            ksrc += 64 * MB;
            vsrc0 += 64;
            vsrc1 += 64;
        }

        const u16* KtC = Kt[cur];
        const u16* VtC = Vtile[cur];

        // K frags: A-frag row = kt*32 + r31, k = ms*16 + hi*8 + j
        bfrag kf[2][2];
        for (int kt = 0; kt < 2; ++kt) {
            const u16* krow = &KtC[(kt * 32 + r31) * 32];
            kf[kt][0] = *(const bfrag*)&krow[((hi    ) ^ ksw) * 8];
            kf[kt][1] = *(const bfrag*)&krow[((2 + hi) ^ ksw) * 8];
        }

        bfrag pf[2][2];   // [kt][kc]: B-frag P[key = kt*32+kc*16+hi*8+j][q=r31]
        for (int kt = 0; kt < 2; ++kt) {
            __builtin_amdgcn_s_setprio(1);
            f32x16 St = __builtin_amdgcn_mfma_f32_32x32x16_bf16(kf[kt][0], qf[0], zero16, 0, 0, 0);
            St = __builtin_amdgcn_mfma_f32_32x32x16_bf16(kf[kt][1], qf[1], St, 0, 0, 0);
            __builtin_amdgcn_s_setprio(0);
            // lane holds S[key = (reg&3)+8*(reg>>2)+4*hi + kt*32][q = r31]
            for (int kc = 0; kc < 2; ++kc) {
                float e0 = EXP2(St[8 * kc + 0]);
                float e1 = EXP2(St[8 * kc + 1]);
                float e2 = EXP2(St[8 * kc + 2]);
                float e3 = EXP2(St[8 * kc + 3]);
                float e4 = EXP2(St[8 * kc + 4]);
                float e5 = EXP2(St[8 * kc + 5]);
                float e6 = EXP2(St[8 * kc + 6]);
                float e7 = EXP2(St[8 * kc + 7]);
                // den partial: float2 tree (pk-add friendly)
                f32x2 p0 = {e0, e1}, p1 = {e2, e3}, p2 = {e4, e5}, p3 = {e6, e7};
                dacc += (p0 + p1) + (p2 + p3);
                // pack: keys kc*16+4hi+{0,1},{2,3} / +8: {0,1},{2,3}
                u32 A0 = cvtpk(e0, e1), A1 = cvtpk(e2, e3);
                u32 B0 = cvtpk(e4, e5), B1 = cvtpk(e6, e7);
                u32 w0, w1, w2, w3;
                plswap(A0, B0, w0, w2);   // w0: keys {0,1}; w2: keys {4,5}  (+kc*16+hi*8)
                plswap(A1, B1, w1, w3);   // w1: keys {2,3}; w3: keys {6,7}
                uint4 words = { w0, w1, w2, w3 };
                pf[kt][kc] = __builtin_bit_cast(bfrag, words);
            }
        }

        __builtin_amdgcn_s_setprio(1);
        for (int dt = 0; dt < 2; ++dt) {
            const u16* vrow = &VtC[(dt * 32 + r31) * 64];
            for (int kt = 0; kt < 2; ++kt)
                for (int kc = 0; kc < 2; ++kc) {
                    bfrag vf = *(const bfrag*)&vrow[(((kt * 4 + kc * 2 + hi) ^ vsw) * 8)];
                    Oa[dt] = __builtin_amdgcn_mfma_f32_32x32x16_bf16(vf, pf[kt][kc], Oa[dt], 0, 0, 0);
                }
        }
        __builtin_amdgcn_s_setprio(0);
    }

    // ---- finish den: self-half + partner-half (lane r31 <-> r31+32, same q)
    float dsum = dacc[0] + dacc[1];
    u32 o0, o1;
    plswap(__builtin_bit_cast(u32, dsum), __builtin_bit_cast(u32, dsum), o0, o1);
    float den = __builtin_bit_cast(float, o0) + __builtin_bit_cast(float, o1);

    // epilogue: lane owns q = q0w + r31; cols d = dt*32 + 8*g + 4*hi + i
    {
        float inv = 1.0f / den;
        u16* aob = AO + (size_t)(b * SEQ + q0w + r31) * DM + h * HD;
        for (int dt = 0; dt < 2; ++dt)
            for (int g = 0; g < 4; ++g) {
                u16 t4[4] = { f2b(Oa[dt][g * 4 + 0] * inv),
                              f2b(Oa[dt][g * 4 + 1] * inv),
                              f2b(Oa[dt][g * 4 + 2] * inv),
                              f2b(Oa[dt][g * 4 + 3] * inv) };
                *(uint2*)&aob[dt * 32 + g * 8 + hi * 4] = *(uint2*)t4;
            }
    }
}

// =====================================================================
extern "C" void kernel_launch(void* const* d_in, const int* in_sizes, int n_in,
                              void* d_out, int out_size, void* d_ws, size_t ws_size,
                              hipStream_t stream) {
    const float* x    = (const float*)d_in[0];
    const float* Wq   = (const float*)d_in[1];
    const float* Wk   = (const float*)d_in[2];
    const float* Wv   = (const float*)d_in[3];
    const float* Wenc = (const float*)d_in[4];
    const float* Wo   = (const float*)d_in[5];
    float* out = (float*)d_out;

    const size_t MB1 = (size_t)1024 * 1024;
    char* ws = (char*)d_ws;
    u16* AO   = (u16*)(ws);            // 16M [S,1024]
    u16* Wo_b = (u16*)(ws + 16 * MB1); //  2M
    u16* Bc   = (u16*)(ws + 18 * MB1); //  4M [2048][1024]: rows 0-1023 CqkT, 1024-2047 Wv
    u16* Vt   = (u16*)(ws + 24 * MB1); // 16M [B*H*64, 2048]
    u16* qe   = (u16*)(ws + 48 * MB1); //  8M [B,H,N,32]
    u16* ke   = (u16*)(ws + 56 * MB1); //  8M

    u16* xb = (u16*)d_out;             // 16M bf16 x (d_out scratch; dead before final store)
    u16* wvb = Bc + (size_t)1024 * DM; // Wv bf16 rows of Bc

    cvt3_f32_bf16<<<dim3(STOK * DM / 8 / 256, 3), 256, 0, stream>>>(
        x, Wv, Wo, xb, wvb, Wo_b, STOK * DM / 8, DM * DM / 8);
    build_cqk<<<dim3(8, 32), 256, 0, stream>>>(Wq, Wk, Wenc, Bc);

    gemm_encv<<<dim3(2048 / 128, STOK / 128), 256, 0, stream>>>(xb, Bc, qe, ke, Vt);

    flash_attn<<<dim3(NH, BATCH, SEQ / 128), 256, 0, stream>>>(qe, ke, Vt, AO);

    gemm_bt<64, float><<<dim3(DM / 128, STOK / 64), 256, 0, stream>>>(AO, Wo_b, out, STOK, DM, DM);
}